// Round 1
// baseline (648.459 us; speedup 1.0000x reference)
//
#include <hip/hip_runtime.h>
#include <math.h>

#define BLOCK 256
#define GROUPS_PER_BLOCK (BLOCK / 32)   // 8 samples in flight per block

// One 32-lane group per sample: lane l loads f[s*128 + l*4 .. +3] as float4
// (contiguous 512B per sample -> fully coalesced). Centers live in registers.
__global__ __launch_bounds__(BLOCK, 4) void center_loss_main(
    const float* __restrict__ f,
    const float* __restrict__ center,
    const int* __restrict__ t,
    float* __restrict__ ws,   // ws[0]=sum0 ws[1]=sum1 ws[2]=cnt0 ws[3]=cnt1
    int N)
{
    const int lane = threadIdx.x & 31;
    const int grp  = threadIdx.x >> 5;
    const int groups_total = gridDim.x * GROUPS_PER_BLOCK;
    const int g0 = blockIdx.x * GROUPS_PER_BLOCK + grp;

    const float4* __restrict__ f4 = (const float4*)f;
    const float4* __restrict__ c4 = (const float4*)center;
    const float4 c0 = c4[lane];        // center[0][lane*4..lane*4+3]
    const float4 c1 = c4[32 + lane];   // center[1][...]

    float sum0 = 0.f, sum1 = 0.f, cnt0 = 0.f, cnt1 = 0.f;

    for (int s = g0; s < N; s += groups_total) {
        const int cls = t[s];                 // broadcast read (same addr per group)
        const float4 fv = f4[s * 32 + lane];  // max byte offset ~512MB < 2^31
        const float4 cv = (cls == 0) ? c0 : c1;
        const float dx = fv.x - cv.x;
        const float dy = fv.y - cv.y;
        const float dz = fv.z - cv.z;
        const float dw = fv.w - cv.w;
        float ss = dx * dx + dy * dy + dz * dz + dw * dw;
        // reduce across the 32-lane group
        ss += __shfl_down(ss, 16, 32);
        ss += __shfl_down(ss, 8, 32);
        ss += __shfl_down(ss, 4, 32);
        ss += __shfl_down(ss, 2, 32);
        ss += __shfl_down(ss, 1, 32);
        if (lane == 0) {
            const float d = sqrtf(ss);
            if (cls == 0) { sum0 += d; cnt0 += 1.f; }
            else          { sum1 += d; cnt1 += 1.f; }
        }
    }

    // block reduction: 8 group leads -> LDS -> 4 atomics per block
    __shared__ float ls[4][GROUPS_PER_BLOCK];
    if (lane == 0) {
        ls[0][grp] = sum0;
        ls[1][grp] = sum1;
        ls[2][grp] = cnt0;
        ls[3][grp] = cnt1;
    }
    __syncthreads();
    if (threadIdx.x < 4) {
        float v = 0.f;
#pragma unroll
        for (int i = 0; i < GROUPS_PER_BLOCK; ++i) v += ls[threadIdx.x][i];
        atomicAdd(&ws[threadIdx.x], v);
    }
}

__global__ void center_loss_final(const float* __restrict__ ws,
                                  float* __restrict__ out)
{
    const float s0 = ws[0], s1 = ws[1], c0 = ws[2], c1 = ws[3];
    float r = 0.f;
    if (c0 > 0.f) r += s0 / c0;
    if (c1 > 0.f) r += s1 / c1;
    out[0] = r;
}

extern "C" void kernel_launch(void* const* d_in, const int* in_sizes, int n_in,
                              void* d_out, int out_size, void* d_ws, size_t ws_size,
                              hipStream_t stream)
{
    const float* f      = (const float*)d_in[0];
    const float* center = (const float*)d_in[1];
    const int*   t      = (const int*)d_in[2];   // integer input -> int32 per harness
    float* out = (float*)d_out;
    float* ws  = (float*)d_ws;

    const int N = in_sizes[0] / 128;   // 1,000,000

    // ws is poisoned to 0xAA before every timed call — zero the accumulators.
    hipMemsetAsync(ws, 0, 4 * sizeof(float), stream);

    const int grid = 2048;  // 8 blocks/CU, grid-stride over 1M samples
    center_loss_main<<<grid, BLOCK, 0, stream>>>(f, center, t, ws, N);
    center_loss_final<<<1, 1, 0, stream>>>(ws, out);
}